// Round 1
// baseline (2759.828 us; speedup 1.0000x reference)
//
#include <hip/hip_runtime.h>

// ---------------------------------------------------------------------------
// DistSAGE: 3-layer GraphSAGE, fp32.
// Per layer l with (n_src, n_dst, n_edges):
//   msg[d]  = sum_{e: dst[e]==d} h[src[e]]          (atomicAdd aggregation)
//   deg[d]  = count of edges into d
//   out     = h[:n_dst] @ W_self + (msg @ W_neigh) * (1/max(deg,1)) + b
//   relu on layers 0,1.
// ---------------------------------------------------------------------------

#define BM 64
#define BN 64
#define BK 16

// ---------------- edge aggregation: gather + atomic scatter-add ------------
__global__ __launch_bounds__(256) void agg_kernel(
    const float* __restrict__ h,
    const int* __restrict__ src, const int* __restrict__ dst,
    float* __restrict__ msg, float* __restrict__ deg,
    int n_edges, int C /* row width in floats, 128 or 256 */)
{
    const int tpe  = C >> 2;                 // threads per edge (float4 each)
    const int lane = threadIdx.x & (tpe - 1);
    const int eidx = blockIdx.x * (blockDim.x / tpe) + threadIdx.x / tpe;
    if (eidx >= n_edges) return;

    const int s = src[eidx];
    const int d = dst[eidx];
    const float4 v = *reinterpret_cast<const float4*>(h + (size_t)s * C + lane * 4);
    float* o = msg + (size_t)d * C + lane * 4;
    atomicAdd(o + 0, v.x);
    atomicAdd(o + 1, v.y);
    atomicAdd(o + 2, v.z);
    atomicAdd(o + 3, v.w);
    if (lane == 0) atomicAdd(deg + d, 1.0f);
}

// ---------------- fused SAGE GEMM ------------------------------------------
// out[r][c] = Aself[r]@Ws[:,c] + inv_deg[r]*(Amsg[r]@Wn[:,c]) + bias[c], relu?
// K-loop runs over virtual length 2K: first half (Aself,Ws), second (Amsg,Wn)
// with Amsg scaled by inv_deg at LDS-load (row scalar => identical math).
__global__ __launch_bounds__(256) void sage_gemm(
    const float* __restrict__ Aself, const float* __restrict__ Amsg,
    const float* __restrict__ deg,
    const float* __restrict__ Ws, const float* __restrict__ Wn,
    const float* __restrict__ bias, float* __restrict__ out,
    int K, int N, int relu)
{
    __shared__ float As[BK][BM + 4];   // stride 68 floats: pad kills conflicts,
                                       // keeps 16B alignment (68*4=272=17*16)
    __shared__ float Bs[BK][BN];

    const int tid = threadIdx.x;
    const int tx  = tid & 15;          // col group: cols c0 + 4*tx .. +3
    const int ty  = tid >> 4;          // row group: rows m0 + 4*ty .. +3
    const int m0  = blockIdx.y * BM;
    const int c0  = blockIdx.x * BN;

    // loader roles
    const int lrow  = tid >> 2;        // 0..63 : A row within tile
    const int lkq   = (tid & 3) << 2;  // 0,4,8,12 : A k sub-offset
    const int bkrow = tid >> 4;        // 0..15 : B k row
    const int bcol  = (tid & 15) << 2; // 0..60 : B col sub-offset

    const float idg = 1.0f / fmaxf(deg[m0 + lrow], 1.0f);

    float acc[4][4] = {{0.f}};

    const int K2 = K * 2;
    for (int ks = 0; ks < K2; ks += BK) {
        const bool ph = (ks >= K);                 // phase: self vs neigh
        const float* __restrict__ A = ph ? Amsg : Aself;
        const float* __restrict__ B = ph ? Wn : Ws;
        const int kl = ph ? (ks - K) : ks;

        float4 av = *reinterpret_cast<const float4*>(
            A + (size_t)(m0 + lrow) * K + kl + lkq);
        if (ph) { av.x *= idg; av.y *= idg; av.z *= idg; av.w *= idg; }
        const float4 bv = *reinterpret_cast<const float4*>(
            B + (size_t)(kl + bkrow) * N + c0 + bcol);

        __syncthreads();   // previous iteration's reads done
        As[lkq + 0][lrow] = av.x;
        As[lkq + 1][lrow] = av.y;
        As[lkq + 2][lrow] = av.z;
        As[lkq + 3][lrow] = av.w;
        *reinterpret_cast<float4*>(&Bs[bkrow][bcol]) = bv;
        __syncthreads();

        #pragma unroll
        for (int k = 0; k < BK; ++k) {
            const float4 a = *reinterpret_cast<const float4*>(&As[k][ty << 2]);
            const float4 b = *reinterpret_cast<const float4*>(&Bs[k][tx << 2]);
            const float ar[4] = {a.x, a.y, a.z, a.w};
            const float br[4] = {b.x, b.y, b.z, b.w};
            #pragma unroll
            for (int i = 0; i < 4; ++i)
                #pragma unroll
                for (int j = 0; j < 4; ++j)
                    acc[i][j] += ar[i] * br[j];
        }
    }

    const float4 bb = *reinterpret_cast<const float4*>(bias + c0 + (tx << 2));
    const float bbr[4] = {bb.x, bb.y, bb.z, bb.w};
    #pragma unroll
    for (int i = 0; i < 4; ++i) {
        float4 r;
        float* rr = reinterpret_cast<float*>(&r);
        #pragma unroll
        for (int j = 0; j < 4; ++j) {
            float v = acc[i][j] + bbr[j];
            rr[j] = relu ? fmaxf(v, 0.f) : v;
        }
        *reinterpret_cast<float4*>(
            out + (size_t)(m0 + (ty << 2) + i) * N + c0 + (tx << 2)) = r;
    }
}

// ---------------------------------------------------------------------------
extern "C" void kernel_launch(void* const* d_in, const int* in_sizes, int n_in,
                              void* d_out, int out_size, void* d_ws, size_t ws_size,
                              hipStream_t stream)
{
    const float* x    = (const float*)d_in[0];
    const int* e0s    = (const int*)d_in[1];
    const int* e0d    = (const int*)d_in[2];
    const int* e1s    = (const int*)d_in[3];
    const int* e1d    = (const int*)d_in[4];
    const int* e2s    = (const int*)d_in[5];
    const int* e2d    = (const int*)d_in[6];
    const float* Ws0  = (const float*)d_in[7];
    const float* Wn0  = (const float*)d_in[8];
    const float* b0   = (const float*)d_in[9];
    const float* Ws1  = (const float*)d_in[10];
    const float* Wn1  = (const float*)d_in[11];
    const float* b1   = (const float*)d_in[12];
    const float* Ws2  = (const float*)d_in[13];
    const float* Wn2  = (const float*)d_in[14];
    const float* b2   = (const float*)d_in[15];
    float* outp       = (float*)d_out;

    // sizes
    const int NE0 = 1013760, ND0 = 67584;
    const int NE1 = 61440,   ND1 = 6144;
    const int NE2 = 5120,    ND2 = 1024;
    const int IN_C = 128, HID = 256, OUT_C = 64;

    char* ws = (char*)d_ws;
    // workspace layout (bytes), with reuse of the msg0 region for h2/msg2/deg2
    const size_t off_msg0 = 0;                       // 67584*128*4 = 34,603,008
    const size_t off_deg0 = 34603008;                // 67584*4     =    270,336
    const size_t off_h1   = 34873344;                // 67584*256*4 = 69,206,016
    const size_t off_msg1 = 104079360;               // 6144*256*4  =  6,291,456
    const size_t off_deg1 = 110370816;               // 6144*4      =     24,576
    const size_t off_h2   = 0;                       // 6144*256*4 (reuse msg0)
    const size_t off_msg2 = 6291456;                 // 1024*256*4  =  1,048,576
    const size_t off_deg2 = 7340032;                 // 1024*4

    float* msg0 = (float*)(ws + off_msg0);
    float* deg0 = (float*)(ws + off_deg0);
    float* h1   = (float*)(ws + off_h1);
    float* msg1 = (float*)(ws + off_msg1);
    float* deg1 = (float*)(ws + off_deg1);
    float* h2   = (float*)(ws + off_h2);
    float* msg2 = (float*)(ws + off_msg2);
    float* deg2 = (float*)(ws + off_deg2);

    // ---------------- layer 0 ----------------
    hipMemsetAsync(ws + off_msg0, 0, 34603008 + 270336, stream);  // msg0+deg0
    {
        const int epb = 256 / (IN_C / 4);   // 8 edges per block
        const int grid = (NE0 + epb - 1) / epb;
        agg_kernel<<<grid, 256, 0, stream>>>(x, e0s, e0d, msg0, deg0, NE0, IN_C);
    }
    sage_gemm<<<dim3(HID / BN, ND0 / BM), 256, 0, stream>>>(
        x, msg0, deg0, Ws0, Wn0, b0, h1, IN_C, HID, 1);

    // ---------------- layer 1 ----------------
    hipMemsetAsync(ws + off_msg1, 0, 6291456 + 24576, stream);    // msg1+deg1
    {
        const int epb = 256 / (HID / 4);    // 4 edges per block
        const int grid = (NE1 + epb - 1) / epb;
        agg_kernel<<<grid, 256, 0, stream>>>(h1, e1s, e1d, msg1, deg1, NE1, HID);
    }
    sage_gemm<<<dim3(HID / BN, ND1 / BM), 256, 0, stream>>>(
        h1, msg1, deg1, Ws1, Wn1, b1, h2, HID, HID, 1);

    // ---------------- layer 2 ----------------
    hipMemsetAsync(ws + off_msg2, 0, 1048576 + 4096, stream);     // msg2+deg2
    {
        const int epb = 256 / (HID / 4);    // 4 edges per block
        const int grid = (NE2 + epb - 1) / epb;
        agg_kernel<<<grid, 256, 0, stream>>>(h2, e2s, e2d, msg2, deg2, NE2, HID);
    }
    sage_gemm<<<dim3(OUT_C / BN, ND2 / BM), 256, 0, stream>>>(
        h2, msg2, deg2, Ws2, Wn2, b2, outp, HID, OUT_C, 0);

    (void)in_sizes; (void)n_in; (void)out_size; (void)ws_size;
}